// Round 10
// baseline (63.968 us; speedup 1.0000x reference)
//
#include <hip/hip_runtime.h>
#include <hip/hip_bf16.h>

#define D_MODEL 1024
#define D_STATE 16
#define BATCH   4
#define SEQ     2048
#define ROWS    (BATCH*SEQ)   // 8192
#define WIN     64            // FIR window; decay<=0.55 => decay^64 < 1e-16

typedef float f32x4 __attribute__((ext_vector_type(4)));   // native vec for nontemporal

// ---------------------------------------------------------------------------
// K1: blocks 0..1023 -> bx projection (8 rows each); blocks 1024..1039 -> Kbar.
// (R7-proven)
// ---------------------------------------------------------------------------
#define K1_ROWS 8
__global__ __launch_bounds__(256, 4) void k_proj(const float* __restrict__ x,
                                                 const float* __restrict__ Bw,
                                                 const float* __restrict__ A_log,
                                                 float* __restrict__ bx,
                                                 float* __restrict__ KbarT) {
    __shared__ float xs[K1_ROWS][1024];               // 32 KB (aliased by kbar path)
    __shared__ float red[4][8][K1_ROWS][2];           // [wave][np][row][q]
    const int tid = threadIdx.x;

    if (blockIdx.x >= ROWS / K1_ROWS) {
        // ---- Kbar path (16 blocks) ----
        const int n = blockIdx.x - ROWS / K1_ROWS;
        float* l2   = &xs[0][0];                      // 1024 floats
        float* kred = &xs[1][0];                      // 4*64 floats
        const int delta = tid & 63;
        const int c     = tid >> 6;
        for (int d = tid; d < D_MODEL; d += 256) {
            float a = A_log[d * D_STATE + n];
            l2[d] = -expf(a) * 1.4426950408889634f;   // log2(decay)
        }
        __syncthreads();
        const float fdelta = (float)delta;
        float acc = 0.f;
        const int d0 = c * 256;
        for (int d = d0; d < d0 + 256; ++d)
            acc += exp2f(fdelta * l2[d]);
        kred[c * WIN + delta] = acc;
        __syncthreads();
        if (tid < WIN)
            KbarT[tid * D_STATE + n] =
                (kred[tid] + kred[WIN + tid] + kred[2 * WIN + tid] + kred[3 * WIN + tid])
                * (1.0f / 1024.0f);
        return;
    }

    // ---- bx path ----
    const int np   = tid & 7;
    const int dblk = tid >> 3;
    const int row0 = blockIdx.x * K1_ROWS;
    const int lane = tid & 63, wid = tid >> 6;

    float4 bw0[8], bw1[8];
    {
        const float4* p0 = reinterpret_cast<const float4*>(Bw + (size_t)(2 * np    ) * 1024 + dblk * 32);
        const float4* p1 = reinterpret_cast<const float4*>(Bw + (size_t)(2 * np + 1) * 1024 + dblk * 32);
#pragma unroll
        for (int j = 0; j < 8; ++j) { bw0[j] = p0[j]; bw1[j] = p1[j]; }
    }

    const int chunk = tid >> 3;
    const int slotw = ((tid & 7) + chunk) & 7;
#pragma unroll
    for (int r = 0; r < K1_ROWS; ++r) {
        float4 v = reinterpret_cast<const float4*>(x + (size_t)(row0 + r) * 1024)[tid];
        *reinterpret_cast<float4*>(&xs[r][chunk * 32 + slotw * 4]) = v;
    }
    __syncthreads();

    float a0[K1_ROWS], a1[K1_ROWS];
#pragma unroll
    for (int r = 0; r < K1_ROWS; ++r) { a0[r] = 0.f; a1[r] = 0.f; }

#pragma unroll
    for (int r = 0; r < K1_ROWS; ++r) {
#pragma unroll
        for (int j = 0; j < 8; ++j) {
            const int slot = (j + dblk) & 7;
            float4 xv = *reinterpret_cast<const float4*>(&xs[r][dblk * 32 + slot * 4]);
            a0[r] = fmaf(xv.x, bw0[j].x, a0[r]); a0[r] = fmaf(xv.y, bw0[j].y, a0[r]);
            a0[r] = fmaf(xv.z, bw0[j].z, a0[r]); a0[r] = fmaf(xv.w, bw0[j].w, a0[r]);
            a1[r] = fmaf(xv.x, bw1[j].x, a1[r]); a1[r] = fmaf(xv.y, bw1[j].y, a1[r]);
            a1[r] = fmaf(xv.z, bw1[j].z, a1[r]); a1[r] = fmaf(xv.w, bw1[j].w, a1[r]);
        }
    }

#pragma unroll
    for (int r = 0; r < K1_ROWS; ++r) {
        float v0 = a0[r], v1 = a1[r];
        v0 += __shfl_xor(v0, 8);  v1 += __shfl_xor(v1, 8);
        v0 += __shfl_xor(v0, 16); v1 += __shfl_xor(v1, 16);
        v0 += __shfl_xor(v0, 32); v1 += __shfl_xor(v1, 32);
        a0[r] = v0; a1[r] = v1;
    }
    if (lane < 8) {
#pragma unroll
        for (int r = 0; r < K1_ROWS; ++r) {
            red[wid][lane][r][0] = a0[r];
            red[wid][lane][r][1] = a1[r];
        }
    }
    __syncthreads();
    if (tid < K1_ROWS * 16) {
        const int r = tid >> 4, n = tid & 15;
        float v = red[0][n >> 1][r][n & 1] + red[1][n >> 1][r][n & 1]
                + red[2][n >> 1][r][n & 1] + red[3][n >> 1][r][n & 1];
        bx[(size_t)(row0 + r) * D_STATE + n] = v;
    }
}

// ---------------------------------------------------------------------------
// K2: FIR, float4 over n. 256 thr = 64 rows x 4 n-quads, grid 128. (R5-proven)
// ---------------------------------------------------------------------------
__global__ __launch_bounds__(256) void k_fir(const float* __restrict__ bx,
                                             const float* __restrict__ KbarT,
                                             float* __restrict__ hm) {
    __shared__ float4 kb4[WIN][4];
    const int tid = threadIdx.x;
    kb4[tid >> 2][tid & 3] = reinterpret_cast<const float4*>(KbarT)[tid];
    __syncthreads();

    const int nq  = tid & 3;
    const int row = blockIdx.x * 64 + (tid >> 2);
    const int t   = row & (SEQ - 1);
    const float4* bp = reinterpret_cast<const float4*>(bx + (size_t)row * D_STATE) + nq;
    float4 acc = {0.f, 0.f, 0.f, 0.f};
    if (t >= WIN - 1) {
#pragma unroll
        for (int dl = 0; dl < WIN; ++dl) {
            float4 b = bp[-(ptrdiff_t)dl * 4];
            float4 k = kb4[dl][nq];
            acc.x = fmaf(k.x, b.x, acc.x); acc.y = fmaf(k.y, b.y, acc.y);
            acc.z = fmaf(k.z, b.z, acc.z); acc.w = fmaf(k.w, b.w, acc.w);
        }
    } else {
        for (int dl = 0; dl <= t; ++dl) {
            float4 b = bp[-(ptrdiff_t)dl * 4];
            float4 k = kb4[dl][nq];
            acc.x = fmaf(k.x, b.x, acc.x); acc.y = fmaf(k.y, b.y, acc.y);
            acc.z = fmaf(k.z, b.z, acc.z); acc.w = fmaf(k.w, b.w, acc.w);
        }
    }
    reinterpret_cast<float4*>(hm + (size_t)row * D_STATE)[nq] = acc;
}

// ---------------------------------------------------------------------------
// K3: y = hm @ C_w^T + D*x ; out = LN(y)*gamma + beta.
// (a) hm tile staged to LDS in one load round; (b) x loads up front;
// (c) nontemporal out stores via native ext_vector f32x4.
// ---------------------------------------------------------------------------
#define KO_ROWS 4
__global__ __launch_bounds__(256, 4) void k_out(const float* __restrict__ x,
                                                const float* __restrict__ hm,
                                                const float* __restrict__ Cw,
                                                const float* __restrict__ Dp,
                                                const float* __restrict__ gamma,
                                                const float* __restrict__ beta,
                                                float* __restrict__ out) {
    const int tid = threadIdx.x;
    const int row0 = blockIdx.x * KO_ROWS;
    const int lane = tid & 63, wid = tid >> 6;
    __shared__ float4 hm4[KO_ROWS][4];
    __shared__ float red_s[KO_ROWS][4], red_q[KO_ROWS][4];

    // (a) stage hm tile: 16 float4, one per thread 0..15 — single L2 round
    if (tid < KO_ROWS * 4)
        hm4[tid >> 2][tid & 3] =
            reinterpret_cast<const float4*>(hm + (size_t)(row0 + (tid >> 2)) * D_STATE)[tid & 3];

    // (b) all x loads up front (independent, 64B/thread in flight)
    float4 xq[KO_ROWS];
#pragma unroll
    for (int r = 0; r < KO_ROWS; ++r)
        xq[r] = reinterpret_cast<const float4*>(x + (size_t)(row0 + r) * D_MODEL)[tid];

    // cw[j][q] = C_w[4*tid+j][4q .. 4q+3]
    float4 cw[4][4];
#pragma unroll
    for (int j = 0; j < 4; ++j) {
        const float4* p = reinterpret_cast<const float4*>(Cw + (size_t)(tid * 4 + j) * D_STATE);
#pragma unroll
        for (int q = 0; q < 4; ++q) cw[j][q] = p[q];
    }
    const float4 Dq = reinterpret_cast<const float4*>(Dp)[tid];
    const float4 gq = reinterpret_cast<const float4*>(gamma)[tid];
    const float4 bq = reinterpret_cast<const float4*>(beta)[tid];
    __syncthreads();   // hm4 ready

    float4 y[KO_ROWS];
#pragma unroll
    for (int r = 0; r < KO_ROWS; ++r) {
        const float4 h0 = hm4[r][0], h1 = hm4[r][1], h2 = hm4[r][2], h3 = hm4[r][3];
        float4 v;
#pragma unroll
        for (int j = 0; j < 4; ++j) {
            float a = 0.f;
            a = fmaf(h0.x, cw[j][0].x, a); a = fmaf(h0.y, cw[j][0].y, a);
            a = fmaf(h0.z, cw[j][0].z, a); a = fmaf(h0.w, cw[j][0].w, a);
            a = fmaf(h1.x, cw[j][1].x, a); a = fmaf(h1.y, cw[j][1].y, a);
            a = fmaf(h1.z, cw[j][1].z, a); a = fmaf(h1.w, cw[j][1].w, a);
            a = fmaf(h2.x, cw[j][2].x, a); a = fmaf(h2.y, cw[j][2].y, a);
            a = fmaf(h2.z, cw[j][2].z, a); a = fmaf(h2.w, cw[j][2].w, a);
            a = fmaf(h3.x, cw[j][3].x, a); a = fmaf(h3.y, cw[j][3].y, a);
            a = fmaf(h3.z, cw[j][3].z, a); a = fmaf(h3.w, cw[j][3].w, a);
            ((float*)&v)[j] = a;
        }
        v.x = fmaf(Dq.x, xq[r].x, v.x);
        v.y = fmaf(Dq.y, xq[r].y, v.y);
        v.z = fmaf(Dq.z, xq[r].z, v.z);
        v.w = fmaf(Dq.w, xq[r].w, v.w);
        y[r] = v;

        float s  = v.x + v.y + v.z + v.w;
        float sq = v.x*v.x + v.y*v.y + v.z*v.z + v.w*v.w;
        s += __shfl_xor(s, 1);  sq += __shfl_xor(sq, 1);
        s += __shfl_xor(s, 2);  sq += __shfl_xor(sq, 2);
        s += __shfl_xor(s, 4);  sq += __shfl_xor(sq, 4);
        s += __shfl_xor(s, 8);  sq += __shfl_xor(sq, 8);
        s += __shfl_xor(s, 16); sq += __shfl_xor(sq, 16);
        s += __shfl_xor(s, 32); sq += __shfl_xor(sq, 32);
        if (lane == 0) { red_s[r][wid] = s; red_q[r][wid] = sq; }
    }
    __syncthreads();

#pragma unroll
    for (int r = 0; r < KO_ROWS; ++r) {
        const size_t row = row0 + r;
        const float ssum = red_s[r][0] + red_s[r][1] + red_s[r][2] + red_s[r][3];
        const float ssq  = red_q[r][0] + red_q[r][1] + red_q[r][2] + red_q[r][3];
        const float mu   = ssum * (1.0f / 1024.0f);
        const float var  = ssq * (1.0f / 1024.0f) - mu * mu;
        const float inv  = rsqrtf(var + 1e-5f);
        const float4 v = y[r];
        f32x4 o;
        o.x = fmaf((v.x - mu) * inv, gq.x, bq.x);
        o.y = fmaf((v.y - mu) * inv, gq.y, bq.y);
        o.z = fmaf((v.z - mu) * inv, gq.z, bq.z);
        o.w = fmaf((v.w - mu) * inv, gq.w, bq.w);
        // (c) nontemporal: out is never re-read; keep L2 for x/hm
        __builtin_nontemporal_store(o, reinterpret_cast<f32x4*>(out + row * D_MODEL) + tid);
    }
}

extern "C" void kernel_launch(void* const* d_in, const int* in_sizes, int n_in,
                              void* d_out, int out_size, void* d_ws, size_t ws_size,
                              hipStream_t stream) {
    (void)in_sizes; (void)n_in; (void)out_size; (void)ws_size;
    const float* x     = (const float*)d_in[0];
    const float* A_log = (const float*)d_in[1];
    const float* B_w   = (const float*)d_in[2];
    const float* C_w   = (const float*)d_in[3];
    const float* Dp    = (const float*)d_in[4];
    const float* gamma = (const float*)d_in[5];
    const float* beta  = (const float*)d_in[6];
    float* out = (float*)d_out;

    float* bx = (float*)d_ws;                       // ROWS*16 floats (512 KB)
    float* kb = bx + (size_t)ROWS * D_STATE;        // WIN*16 floats (4 KB)
    float* hm = kb + WIN * D_STATE;                 // ROWS*16 floats (512 KB)

    k_proj<<<ROWS / K1_ROWS + D_STATE, 256, 0, stream>>>(x, B_w, A_log, bx, kb);
    k_fir <<<ROWS / 64,                256, 0, stream>>>(bx, kb, hm);
    k_out <<<ROWS / KO_ROWS,           256, 0, stream>>>(x, hm, C_w, Dp, gamma, beta, out);
}

// Round 11
// 56.832 us; speedup vs baseline: 1.1256x; 1.1256x over previous
//
#include <hip/hip_runtime.h>
#include <hip/hip_bf16.h>

#define D_MODEL 1024
#define D_STATE 16
#define BATCH   4
#define SEQ     2048
#define ROWS    (BATCH*SEQ)   // 8192
#define WIN     64            // FIR window; decay<=0.55 => decay^64 < 1e-16

// ---------------------------------------------------------------------------
// K1: blocks 0..1023 -> bx projection (8 rows each); blocks 1024..1039 -> Kbar.
// (R7-proven, unchanged)
// ---------------------------------------------------------------------------
#define K1_ROWS 8
__global__ __launch_bounds__(256, 4) void k_proj(const float* __restrict__ x,
                                                 const float* __restrict__ Bw,
                                                 const float* __restrict__ A_log,
                                                 float* __restrict__ bx,
                                                 float* __restrict__ KbarT) {
    __shared__ float xs[K1_ROWS][1024];               // 32 KB (aliased by kbar path)
    __shared__ float red[4][8][K1_ROWS][2];           // [wave][np][row][q]
    const int tid = threadIdx.x;

    if (blockIdx.x >= ROWS / K1_ROWS) {
        // ---- Kbar path (16 blocks) ----
        const int n = blockIdx.x - ROWS / K1_ROWS;
        float* l2   = &xs[0][0];                      // 1024 floats
        float* kred = &xs[1][0];                      // 4*64 floats
        const int delta = tid & 63;
        const int c     = tid >> 6;
        for (int d = tid; d < D_MODEL; d += 256) {
            float a = A_log[d * D_STATE + n];
            l2[d] = -expf(a) * 1.4426950408889634f;   // log2(decay)
        }
        __syncthreads();
        const float fdelta = (float)delta;
        float acc = 0.f;
        const int d0 = c * 256;
        for (int d = d0; d < d0 + 256; ++d)
            acc += exp2f(fdelta * l2[d]);
        kred[c * WIN + delta] = acc;
        __syncthreads();
        if (tid < WIN)
            KbarT[tid * D_STATE + n] =
                (kred[tid] + kred[WIN + tid] + kred[2 * WIN + tid] + kred[3 * WIN + tid])
                * (1.0f / 1024.0f);
        return;
    }

    // ---- bx path ----
    const int np   = tid & 7;
    const int dblk = tid >> 3;
    const int row0 = blockIdx.x * K1_ROWS;
    const int lane = tid & 63, wid = tid >> 6;

    float4 bw0[8], bw1[8];
    {
        const float4* p0 = reinterpret_cast<const float4*>(Bw + (size_t)(2 * np    ) * 1024 + dblk * 32);
        const float4* p1 = reinterpret_cast<const float4*>(Bw + (size_t)(2 * np + 1) * 1024 + dblk * 32);
#pragma unroll
        for (int j = 0; j < 8; ++j) { bw0[j] = p0[j]; bw1[j] = p1[j]; }
    }

    const int chunk = tid >> 3;
    const int slotw = ((tid & 7) + chunk) & 7;
#pragma unroll
    for (int r = 0; r < K1_ROWS; ++r) {
        float4 v = reinterpret_cast<const float4*>(x + (size_t)(row0 + r) * 1024)[tid];
        *reinterpret_cast<float4*>(&xs[r][chunk * 32 + slotw * 4]) = v;
    }
    __syncthreads();

    float a0[K1_ROWS], a1[K1_ROWS];
#pragma unroll
    for (int r = 0; r < K1_ROWS; ++r) { a0[r] = 0.f; a1[r] = 0.f; }

#pragma unroll
    for (int r = 0; r < K1_ROWS; ++r) {
#pragma unroll
        for (int j = 0; j < 8; ++j) {
            const int slot = (j + dblk) & 7;
            float4 xv = *reinterpret_cast<const float4*>(&xs[r][dblk * 32 + slot * 4]);
            a0[r] = fmaf(xv.x, bw0[j].x, a0[r]); a0[r] = fmaf(xv.y, bw0[j].y, a0[r]);
            a0[r] = fmaf(xv.z, bw0[j].z, a0[r]); a0[r] = fmaf(xv.w, bw0[j].w, a0[r]);
            a1[r] = fmaf(xv.x, bw1[j].x, a1[r]); a1[r] = fmaf(xv.y, bw1[j].y, a1[r]);
            a1[r] = fmaf(xv.z, bw1[j].z, a1[r]); a1[r] = fmaf(xv.w, bw1[j].w, a1[r]);
        }
    }

#pragma unroll
    for (int r = 0; r < K1_ROWS; ++r) {
        float v0 = a0[r], v1 = a1[r];
        v0 += __shfl_xor(v0, 8);  v1 += __shfl_xor(v1, 8);
        v0 += __shfl_xor(v0, 16); v1 += __shfl_xor(v1, 16);
        v0 += __shfl_xor(v0, 32); v1 += __shfl_xor(v1, 32);
        a0[r] = v0; a1[r] = v1;
    }
    if (lane < 8) {
#pragma unroll
        for (int r = 0; r < K1_ROWS; ++r) {
            red[wid][lane][r][0] = a0[r];
            red[wid][lane][r][1] = a1[r];
        }
    }
    __syncthreads();
    if (tid < K1_ROWS * 16) {
        const int r = tid >> 4, n = tid & 15;
        float v = red[0][n >> 1][r][n & 1] + red[1][n >> 1][r][n & 1]
                + red[2][n >> 1][r][n & 1] + red[3][n >> 1][r][n & 1];
        bx[(size_t)(row0 + r) * D_STATE + n] = v;
    }
}

// ---------------------------------------------------------------------------
// K2 (fused FIR + matvec + LN): 256 thr, 8 rows/block, grid 1024.
// FIR phase: bx window (71 rows) staged to LDS as float4; tid=(r,dc,nq) does
// 8 taps x float4; 3-fold shfl reduce over dc; writes hm4. No hm global
// round-trip, no extra launch. Matvec/LN phase identical to R7's proven k_out.
// ---------------------------------------------------------------------------
#define KO_ROWS 8
__global__ __launch_bounds__(256, 4) void k_tail(const float* __restrict__ x,
                                                 const float* __restrict__ bxg,
                                                 const float* __restrict__ KbarT,
                                                 const float* __restrict__ Cw,
                                                 const float* __restrict__ Dp,
                                                 const float* __restrict__ gamma,
                                                 const float* __restrict__ beta,
                                                 float* __restrict__ out) {
    const int tid = threadIdx.x;
    const int row0 = blockIdx.x * KO_ROWS;
    const int lane = tid & 63, wid = tid >> 6;
    __shared__ float4 bwin[71][4];                 // rows row0-63 .. row0+7
    __shared__ float4 kb4[WIN][4];                 // [delta][nq]
    __shared__ float4 hm4[KO_ROWS][4];
    __shared__ float red_s[2][4][4], red_q[2][4][4];

    // ---- stage kb (256 float4) and bx window (284 float4) ----
    kb4[tid >> 2][tid & 3] = reinterpret_cast<const float4*>(KbarT)[tid];
    const float4* bx4 = reinterpret_cast<const float4*>(bxg);
    for (int f = tid; f < 71 * 4; f += 256) {
        const int j = f >> 2, q = f & 3;
        long g = (long)row0 - 63 + j;
        if (g < 0) g = 0;                          // clamped entries masked below
        bwin[j][q] = bx4[g * 4 + q];
    }
    __syncthreads();

    // ---- FIR: tid = r*32 + dc*4 + nq ----
    {
        const int r_f = tid >> 5, dc = (tid >> 2) & 7, nq = tid & 3;
        const int t0 = row0 & (SEQ - 1);
        float4 acc = {0.f, 0.f, 0.f, 0.f};
        if (t0 >= WIN) {                           // full window for all 8 rows
#pragma unroll
            for (int j = 0; j < 8; ++j) {
                const int delta = dc * 8 + j;
                const float4 b = bwin[63 + r_f - delta][nq];
                const float4 k = kb4[delta][nq];
                acc.x = fmaf(k.x, b.x, acc.x); acc.y = fmaf(k.y, b.y, acc.y);
                acc.z = fmaf(k.z, b.z, acc.z); acc.w = fmaf(k.w, b.w, acc.w);
            }
        } else {                                   // warm-up rows: mask taps
            const int t = t0 + r_f;
#pragma unroll
            for (int j = 0; j < 8; ++j) {
                const int delta = dc * 8 + j;
                if (delta <= t) {
                    const float4 b = bwin[63 + r_f - delta][nq];
                    const float4 k = kb4[delta][nq];
                    acc.x = fmaf(k.x, b.x, acc.x); acc.y = fmaf(k.y, b.y, acc.y);
                    acc.z = fmaf(k.z, b.z, acc.z); acc.w = fmaf(k.w, b.w, acc.w);
                }
            }
        }
        // reduce over dc (lane bits 2..4): xor 4, 8, 16
#pragma unroll
        for (int off = 4; off <= 16; off <<= 1) {
            acc.x += __shfl_xor(acc.x, off);
            acc.y += __shfl_xor(acc.y, off);
            acc.z += __shfl_xor(acc.z, off);
            acc.w += __shfl_xor(acc.w, off);
        }
        if (dc == 0) hm4[r_f][nq] = acc;
    }
    __syncthreads();

    // ---- matvec + D*x + LN (R7-proven structure) ----
    float4 cw[4][4];
#pragma unroll
    for (int j = 0; j < 4; ++j) {
        const float4* p = reinterpret_cast<const float4*>(Cw + (size_t)(tid * 4 + j) * D_STATE);
#pragma unroll
        for (int q = 0; q < 4; ++q) cw[j][q] = p[q];
    }
    const float4 Dq = reinterpret_cast<const float4*>(Dp)[tid];
    const float4 gq = reinterpret_cast<const float4*>(gamma)[tid];
    const float4 bq = reinterpret_cast<const float4*>(beta)[tid];

    for (int h = 0; h < 2; ++h) {
        float4 y[4];
#pragma unroll
        for (int rr = 0; rr < 4; ++rr) {
            const int r = h * 4 + rr;
            const size_t row = row0 + r;
            const float4 h0 = hm4[r][0], h1 = hm4[r][1], h2 = hm4[r][2], h3 = hm4[r][3];
            const float4 xq = reinterpret_cast<const float4*>(x + row * D_MODEL)[tid];

            float4 v;
#pragma unroll
            for (int j = 0; j < 4; ++j) {
                float a = 0.f;
                a = fmaf(h0.x, cw[j][0].x, a); a = fmaf(h0.y, cw[j][0].y, a);
                a = fmaf(h0.z, cw[j][0].z, a); a = fmaf(h0.w, cw[j][0].w, a);
                a = fmaf(h1.x, cw[j][1].x, a); a = fmaf(h1.y, cw[j][1].y, a);
                a = fmaf(h1.z, cw[j][1].z, a); a = fmaf(h1.w, cw[j][1].w, a);
                a = fmaf(h2.x, cw[j][2].x, a); a = fmaf(h2.y, cw[j][2].y, a);
                a = fmaf(h2.z, cw[j][2].z, a); a = fmaf(h2.w, cw[j][2].w, a);
                a = fmaf(h3.x, cw[j][3].x, a); a = fmaf(h3.y, cw[j][3].y, a);
                a = fmaf(h3.z, cw[j][3].z, a); a = fmaf(h3.w, cw[j][3].w, a);
                ((float*)&v)[j] = a;
            }
            v.x = fmaf(Dq.x, xq.x, v.x);
            v.y = fmaf(Dq.y, xq.y, v.y);
            v.z = fmaf(Dq.z, xq.z, v.z);
            v.w = fmaf(Dq.w, xq.w, v.w);
            y[rr] = v;

            float s  = v.x + v.y + v.z + v.w;
            float sq = v.x*v.x + v.y*v.y + v.z*v.z + v.w*v.w;
            s += __shfl_xor(s, 1);  sq += __shfl_xor(sq, 1);
            s += __shfl_xor(s, 2);  sq += __shfl_xor(sq, 2);
            s += __shfl_xor(s, 4);  sq += __shfl_xor(sq, 4);
            s += __shfl_xor(s, 8);  sq += __shfl_xor(sq, 8);
            s += __shfl_xor(s, 16); sq += __shfl_xor(sq, 16);
            s += __shfl_xor(s, 32); sq += __shfl_xor(sq, 32);
            if (lane == 0) { red_s[h][rr][wid] = s; red_q[h][rr][wid] = sq; }
        }
        __syncthreads();

#pragma unroll
        for (int rr = 0; rr < 4; ++rr) {
            const int r = h * 4 + rr;
            const size_t row = row0 + r;
            const float ssum = red_s[h][rr][0] + red_s[h][rr][1] + red_s[h][rr][2] + red_s[h][rr][3];
            const float ssq  = red_q[h][rr][0] + red_q[h][rr][1] + red_q[h][rr][2] + red_q[h][rr][3];
            const float mu   = ssum * (1.0f / 1024.0f);
            const float var  = ssq * (1.0f / 1024.0f) - mu * mu;
            const float inv  = rsqrtf(var + 1e-5f);
            const float4 v = y[rr];
            float4 o;
            o.x = fmaf((v.x - mu) * inv, gq.x, bq.x);
            o.y = fmaf((v.y - mu) * inv, gq.y, bq.y);
            o.z = fmaf((v.z - mu) * inv, gq.z, bq.z);
            o.w = fmaf((v.w - mu) * inv, gq.w, bq.w);
            reinterpret_cast<float4*>(out + row * D_MODEL)[tid] = o;
        }
    }
}

extern "C" void kernel_launch(void* const* d_in, const int* in_sizes, int n_in,
                              void* d_out, int out_size, void* d_ws, size_t ws_size,
                              hipStream_t stream) {
    (void)in_sizes; (void)n_in; (void)out_size; (void)ws_size;
    const float* x     = (const float*)d_in[0];
    const float* A_log = (const float*)d_in[1];
    const float* B_w   = (const float*)d_in[2];
    const float* C_w   = (const float*)d_in[3];
    const float* Dp    = (const float*)d_in[4];
    const float* gamma = (const float*)d_in[5];
    const float* beta  = (const float*)d_in[6];
    float* out = (float*)d_out;

    float* bx = (float*)d_ws;                       // ROWS*16 floats (512 KB)
    float* kb = bx + (size_t)ROWS * D_STATE;        // WIN*16 floats (4 KB)

    k_proj<<<ROWS / K1_ROWS + D_STATE, 256, 0, stream>>>(x, B_w, A_log, bx, kb);
    k_tail<<<ROWS / KO_ROWS,           256, 0, stream>>>(x, bx, kb, C_w, Dp, gamma, beta, out);
}

// Round 12
// 49.104 us; speedup vs baseline: 1.3027x; 1.1574x over previous
//
#include <hip/hip_runtime.h>
#include <hip/hip_bf16.h>

#define D_MODEL 1024
#define D_STATE 16
#define BATCH   4
#define SEQ     2048
#define ROWS    (BATCH*SEQ)   // 8192
#define WIN     64            // FIR window; decay<=0.55 => decay^64 < 1e-16

// ---------------------------------------------------------------------------
// K1: blocks 0..15 -> Kbar (scheduled first, overlaps bx wave);
//     blocks 16..1039 -> bx projection (8 rows each). (R7-proven core)
// ---------------------------------------------------------------------------
#define K1_ROWS 8
__global__ __launch_bounds__(256, 4) void k_proj(const float* __restrict__ x,
                                                 const float* __restrict__ Bw,
                                                 const float* __restrict__ A_log,
                                                 float* __restrict__ bx,
                                                 float* __restrict__ KbarT) {
    __shared__ float xs[K1_ROWS][1024];               // 32 KB (aliased by kbar path)
    __shared__ float red[4][8][K1_ROWS][2];           // [wave][np][row][q]
    const int tid = threadIdx.x;

    if (blockIdx.x < D_STATE) {
        // ---- Kbar path (16 blocks, first in dispatch order) ----
        const int n = blockIdx.x;
        float* l2   = &xs[0][0];                      // 1024 floats
        float* kred = &xs[1][0];                      // 4*64 floats
        const int delta = tid & 63;
        const int c     = tid >> 6;
        for (int d = tid; d < D_MODEL; d += 256) {
            float a = A_log[d * D_STATE + n];
            l2[d] = -expf(a) * 1.4426950408889634f;   // log2(decay)
        }
        __syncthreads();
        const float fdelta = (float)delta;
        float acc = 0.f;
        const int d0 = c * 256;
        for (int d = d0; d < d0 + 256; ++d)
            acc += exp2f(fdelta * l2[d]);
        kred[c * WIN + delta] = acc;
        __syncthreads();
        if (tid < WIN)
            KbarT[tid * D_STATE + n] =
                (kred[tid] + kred[WIN + tid] + kred[2 * WIN + tid] + kred[3 * WIN + tid])
                * (1.0f / 1024.0f);
        return;
    }

    // ---- bx path ----
    const int np   = tid & 7;
    const int dblk = tid >> 3;
    const int row0 = (blockIdx.x - D_STATE) * K1_ROWS;
    const int lane = tid & 63, wid = tid >> 6;

    float4 bw0[8], bw1[8];
    {
        const float4* p0 = reinterpret_cast<const float4*>(Bw + (size_t)(2 * np    ) * 1024 + dblk * 32);
        const float4* p1 = reinterpret_cast<const float4*>(Bw + (size_t)(2 * np + 1) * 1024 + dblk * 32);
#pragma unroll
        for (int j = 0; j < 8; ++j) { bw0[j] = p0[j]; bw1[j] = p1[j]; }
    }

    const int chunk = tid >> 3;
    const int slotw = ((tid & 7) + chunk) & 7;
#pragma unroll
    for (int r = 0; r < K1_ROWS; ++r) {
        float4 v = reinterpret_cast<const float4*>(x + (size_t)(row0 + r) * 1024)[tid];
        *reinterpret_cast<float4*>(&xs[r][chunk * 32 + slotw * 4]) = v;
    }
    __syncthreads();

    float a0[K1_ROWS], a1[K1_ROWS];
#pragma unroll
    for (int r = 0; r < K1_ROWS; ++r) { a0[r] = 0.f; a1[r] = 0.f; }

#pragma unroll
    for (int r = 0; r < K1_ROWS; ++r) {
#pragma unroll
        for (int j = 0; j < 8; ++j) {
            const int slot = (j + dblk) & 7;
            float4 xv = *reinterpret_cast<const float4*>(&xs[r][dblk * 32 + slot * 4]);
            a0[r] = fmaf(xv.x, bw0[j].x, a0[r]); a0[r] = fmaf(xv.y, bw0[j].y, a0[r]);
            a0[r] = fmaf(xv.z, bw0[j].z, a0[r]); a0[r] = fmaf(xv.w, bw0[j].w, a0[r]);
            a1[r] = fmaf(xv.x, bw1[j].x, a1[r]); a1[r] = fmaf(xv.y, bw1[j].y, a1[r]);
            a1[r] = fmaf(xv.z, bw1[j].z, a1[r]); a1[r] = fmaf(xv.w, bw1[j].w, a1[r]);
        }
    }

#pragma unroll
    for (int r = 0; r < K1_ROWS; ++r) {
        float v0 = a0[r], v1 = a1[r];
        v0 += __shfl_xor(v0, 8);  v1 += __shfl_xor(v1, 8);
        v0 += __shfl_xor(v0, 16); v1 += __shfl_xor(v1, 16);
        v0 += __shfl_xor(v0, 32); v1 += __shfl_xor(v1, 32);
        a0[r] = v0; a1[r] = v1;
    }
    if (lane < 8) {
#pragma unroll
        for (int r = 0; r < K1_ROWS; ++r) {
            red[wid][lane][r][0] = a0[r];
            red[wid][lane][r][1] = a1[r];
        }
    }
    __syncthreads();
    if (tid < K1_ROWS * 16) {
        const int r = tid >> 4, n = tid & 15;
        float v = red[0][n >> 1][r][n & 1] + red[1][n >> 1][r][n & 1]
                + red[2][n >> 1][r][n & 1] + red[3][n >> 1][r][n & 1];
        bx[(size_t)(row0 + r) * D_STATE + n] = v;
    }
}

// ---------------------------------------------------------------------------
// K2 (fused FIR + matvec + LN): 256 thr, 8 rows/block, grid 1024.
// Changes vs R11: (1) xq[8] prefetched at kernel top (hidden under staging+
// FIR); (2) single 8-row partial-sum group -> 16 independent shfl chains,
// one barrier instead of two; (3) launch_bounds(256,3) for VGPR headroom.
// ---------------------------------------------------------------------------
#define KO_ROWS 8
__global__ __launch_bounds__(256, 3) void k_tail(const float* __restrict__ x,
                                                 const float* __restrict__ bxg,
                                                 const float* __restrict__ KbarT,
                                                 const float* __restrict__ Cw,
                                                 const float* __restrict__ Dp,
                                                 const float* __restrict__ gamma,
                                                 const float* __restrict__ beta,
                                                 float* __restrict__ out) {
    const int tid = threadIdx.x;
    const int row0 = blockIdx.x * KO_ROWS;
    const int lane = tid & 63, wid = tid >> 6;
    __shared__ float4 bwin[71][4];                 // rows row0-63 .. row0+7
    __shared__ float4 kb4[WIN][4];                 // [delta][nq]
    __shared__ float4 hm4[KO_ROWS][4];
    __shared__ float red_s[KO_ROWS][4], red_q[KO_ROWS][4];

    // (1) prefetch all 8 rows of x up front — in flight through staging + FIR
    float4 xq[KO_ROWS];
#pragma unroll
    for (int r = 0; r < KO_ROWS; ++r)
        xq[r] = reinterpret_cast<const float4*>(x + (size_t)(row0 + r) * D_MODEL)[tid];

    // ---- stage kb (256 float4) and bx window (284 float4) ----
    kb4[tid >> 2][tid & 3] = reinterpret_cast<const float4*>(KbarT)[tid];
    const float4* bx4 = reinterpret_cast<const float4*>(bxg);
    for (int f = tid; f < 71 * 4; f += 256) {
        const int j = f >> 2, q = f & 3;
        long g = (long)row0 - 63 + j;
        if (g < 0) g = 0;                          // clamped entries masked below
        bwin[j][q] = bx4[g * 4 + q];
    }
    __syncthreads();

    // ---- FIR: tid = r*32 + dc*4 + nq ----
    {
        const int r_f = tid >> 5, dc = (tid >> 2) & 7, nq = tid & 3;
        const int t0 = row0 & (SEQ - 1);
        float4 acc = {0.f, 0.f, 0.f, 0.f};
        if (t0 >= WIN) {                           // full window for all 8 rows
#pragma unroll
            for (int j = 0; j < 8; ++j) {
                const int delta = dc * 8 + j;
                const float4 b = bwin[63 + r_f - delta][nq];
                const float4 k = kb4[delta][nq];
                acc.x = fmaf(k.x, b.x, acc.x); acc.y = fmaf(k.y, b.y, acc.y);
                acc.z = fmaf(k.z, b.z, acc.z); acc.w = fmaf(k.w, b.w, acc.w);
            }
        } else {                                   // warm-up rows: mask taps
            const int t = t0 + r_f;
#pragma unroll
            for (int j = 0; j < 8; ++j) {
                const int delta = dc * 8 + j;
                if (delta <= t) {
                    const float4 b = bwin[63 + r_f - delta][nq];
                    const float4 k = kb4[delta][nq];
                    acc.x = fmaf(k.x, b.x, acc.x); acc.y = fmaf(k.y, b.y, acc.y);
                    acc.z = fmaf(k.z, b.z, acc.z); acc.w = fmaf(k.w, b.w, acc.w);
                }
            }
        }
#pragma unroll
        for (int off = 4; off <= 16; off <<= 1) {
            acc.x += __shfl_xor(acc.x, off);
            acc.y += __shfl_xor(acc.y, off);
            acc.z += __shfl_xor(acc.z, off);
            acc.w += __shfl_xor(acc.w, off);
        }
        if (dc == 0) hm4[r_f][nq] = acc;
    }
    __syncthreads();

    // ---- matvec + D*x + LN partials: all 8 rows, no intermediate barrier ----
    float4 cw[4][4];
#pragma unroll
    for (int j = 0; j < 4; ++j) {
        const float4* p = reinterpret_cast<const float4*>(Cw + (size_t)(tid * 4 + j) * D_STATE);
#pragma unroll
        for (int q = 0; q < 4; ++q) cw[j][q] = p[q];
    }
    const float4 Dq = reinterpret_cast<const float4*>(Dp)[tid];
    const float4 gq = reinterpret_cast<const float4*>(gamma)[tid];
    const float4 bq = reinterpret_cast<const float4*>(beta)[tid];

    float4 y[KO_ROWS];
#pragma unroll
    for (int r = 0; r < KO_ROWS; ++r) {
        const float4 h0 = hm4[r][0], h1 = hm4[r][1], h2 = hm4[r][2], h3 = hm4[r][3];
        float4 v;
#pragma unroll
        for (int j = 0; j < 4; ++j) {
            float a = 0.f;
            a = fmaf(h0.x, cw[j][0].x, a); a = fmaf(h0.y, cw[j][0].y, a);
            a = fmaf(h0.z, cw[j][0].z, a); a = fmaf(h0.w, cw[j][0].w, a);
            a = fmaf(h1.x, cw[j][1].x, a); a = fmaf(h1.y, cw[j][1].y, a);
            a = fmaf(h1.z, cw[j][1].z, a); a = fmaf(h1.w, cw[j][1].w, a);
            a = fmaf(h2.x, cw[j][2].x, a); a = fmaf(h2.y, cw[j][2].y, a);
            a = fmaf(h2.z, cw[j][2].z, a); a = fmaf(h2.w, cw[j][2].w, a);
            a = fmaf(h3.x, cw[j][3].x, a); a = fmaf(h3.y, cw[j][3].y, a);
            a = fmaf(h3.z, cw[j][3].z, a); a = fmaf(h3.w, cw[j][3].w, a);
            ((float*)&v)[j] = a;
        }
        v.x = fmaf(Dq.x, xq[r].x, v.x);
        v.y = fmaf(Dq.y, xq[r].y, v.y);
        v.z = fmaf(Dq.z, xq[r].z, v.z);
        v.w = fmaf(Dq.w, xq[r].w, v.w);
        y[r] = v;

        float s  = v.x + v.y + v.z + v.w;
        float sq = v.x*v.x + v.y*v.y + v.z*v.z + v.w*v.w;
        s += __shfl_xor(s, 1);  sq += __shfl_xor(sq, 1);
        s += __shfl_xor(s, 2);  sq += __shfl_xor(sq, 2);
        s += __shfl_xor(s, 4);  sq += __shfl_xor(sq, 4);
        s += __shfl_xor(s, 8);  sq += __shfl_xor(sq, 8);
        s += __shfl_xor(s, 16); sq += __shfl_xor(sq, 16);
        s += __shfl_xor(s, 32); sq += __shfl_xor(sq, 32);
        if (lane == 0) { red_s[r][wid] = s; red_q[r][wid] = sq; }
    }
    __syncthreads();

#pragma unroll
    for (int r = 0; r < KO_ROWS; ++r) {
        const size_t row = row0 + r;
        const float ssum = red_s[r][0] + red_s[r][1] + red_s[r][2] + red_s[r][3];
        const float ssq  = red_q[r][0] + red_q[r][1] + red_q[r][2] + red_q[r][3];
        const float mu   = ssum * (1.0f / 1024.0f);
        const float var  = ssq * (1.0f / 1024.0f) - mu * mu;
        const float inv  = rsqrtf(var + 1e-5f);
        const float4 v = y[r];
        float4 o;
        o.x = fmaf((v.x - mu) * inv, gq.x, bq.x);
        o.y = fmaf((v.y - mu) * inv, gq.y, bq.y);
        o.z = fmaf((v.z - mu) * inv, gq.z, bq.z);
        o.w = fmaf((v.w - mu) * inv, gq.w, bq.w);
        reinterpret_cast<float4*>(out + row * D_MODEL)[tid] = o;
    }
}

extern "C" void kernel_launch(void* const* d_in, const int* in_sizes, int n_in,
                              void* d_out, int out_size, void* d_ws, size_t ws_size,
                              hipStream_t stream) {
    (void)in_sizes; (void)n_in; (void)out_size; (void)ws_size;
    const float* x     = (const float*)d_in[0];
    const float* A_log = (const float*)d_in[1];
    const float* B_w   = (const float*)d_in[2];
    const float* C_w   = (const float*)d_in[3];
    const float* Dp    = (const float*)d_in[4];
    const float* gamma = (const float*)d_in[5];
    const float* beta  = (const float*)d_in[6];
    float* out = (float*)d_out;

    float* bx = (float*)d_ws;                       // ROWS*16 floats (512 KB)
    float* kb = bx + (size_t)ROWS * D_STATE;        // WIN*16 floats (4 KB)

    k_proj<<<ROWS / K1_ROWS + D_STATE, 256, 0, stream>>>(x, B_w, A_log, bx, kb);
    k_tail<<<ROWS / KO_ROWS,           256, 0, stream>>>(x, bx, kb, C_w, Dp, gamma, beta, out);
}

// Round 13
// 47.917 us; speedup vs baseline: 1.3350x; 1.0248x over previous
//
#include <hip/hip_runtime.h>
#include <hip/hip_bf16.h>

#define D_MODEL 1024
#define D_STATE 16
#define BATCH   4
#define SEQ     2048
#define ROWS    (BATCH*SEQ)   // 8192
#define WIN     64            // FIR window; decay<=0.55 => decay^64 < 1e-16

// ---------------------------------------------------------------------------
// K1: blocks 0..15 -> Kbar; blocks 16..1039 -> bx projection (8 rows each).
// R12 core + async-STAGE split: all global loads (x rows, B_w slices) issued
// into registers BEFORE any LDS write — one latency drain, not eight.
// ---------------------------------------------------------------------------
#define K1_ROWS 8
__global__ __launch_bounds__(256, 4) void k_proj(const float* __restrict__ x,
                                                 const float* __restrict__ Bw,
                                                 const float* __restrict__ A_log,
                                                 float* __restrict__ bx,
                                                 float* __restrict__ KbarT) {
    __shared__ float xs[K1_ROWS][1024];               // 32 KB (aliased by kbar path)
    __shared__ float red[4][8][K1_ROWS][2];           // [wave][np][row][q]
    const int tid = threadIdx.x;

    if (blockIdx.x < D_STATE) {
        // ---- Kbar path (16 blocks, first in dispatch order) ----
        const int n = blockIdx.x;
        float* l2   = &xs[0][0];                      // 1024 floats
        float* kred = &xs[1][0];                      // 4*64 floats
        const int delta = tid & 63;
        const int c     = tid >> 6;
        for (int d = tid; d < D_MODEL; d += 256) {
            float a = A_log[d * D_STATE + n];
            l2[d] = -expf(a) * 1.4426950408889634f;   // log2(decay)
        }
        __syncthreads();
        const float fdelta = (float)delta;
        float acc = 0.f;
        const int d0 = c * 256;
        for (int d = d0; d < d0 + 256; ++d)
            acc += exp2f(fdelta * l2[d]);
        kred[c * WIN + delta] = acc;
        __syncthreads();
        if (tid < WIN)
            KbarT[tid * D_STATE + n] =
                (kred[tid] + kred[WIN + tid] + kred[2 * WIN + tid] + kred[3 * WIN + tid])
                * (1.0f / 1024.0f);
        return;
    }

    // ---- bx path ----
    const int np   = tid & 7;
    const int dblk = tid >> 3;
    const int row0 = (blockIdx.x - D_STATE) * K1_ROWS;
    const int lane = tid & 63, wid = tid >> 6;

    // (1) issue ALL x loads first (deepest latency), into regs
    float4 xr[K1_ROWS];
#pragma unroll
    for (int r = 0; r < K1_ROWS; ++r)
        xr[r] = reinterpret_cast<const float4*>(x + (size_t)(row0 + r) * 1024)[tid];

    // (2) B_w loads fill the x-latency shadow
    float4 bw0[8], bw1[8];
    {
        const float4* p0 = reinterpret_cast<const float4*>(Bw + (size_t)(2 * np    ) * 1024 + dblk * 32);
        const float4* p1 = reinterpret_cast<const float4*>(Bw + (size_t)(2 * np + 1) * 1024 + dblk * 32);
#pragma unroll
        for (int j = 0; j < 8; ++j) { bw0[j] = p0[j]; bw1[j] = p1[j]; }
    }

    // (3) LDS writes (swizzled), one drain
    const int chunk = tid >> 3;
    const int slotw = ((tid & 7) + chunk) & 7;
#pragma unroll
    for (int r = 0; r < K1_ROWS; ++r)
        *reinterpret_cast<float4*>(&xs[r][chunk * 32 + slotw * 4]) = xr[r];
    __syncthreads();

    float a0[K1_ROWS], a1[K1_ROWS];
#pragma unroll
    for (int r = 0; r < K1_ROWS; ++r) { a0[r] = 0.f; a1[r] = 0.f; }

#pragma unroll
    for (int r = 0; r < K1_ROWS; ++r) {
#pragma unroll
        for (int j = 0; j < 8; ++j) {
            const int slot = (j + dblk) & 7;
            float4 xv = *reinterpret_cast<const float4*>(&xs[r][dblk * 32 + slot * 4]);
            a0[r] = fmaf(xv.x, bw0[j].x, a0[r]); a0[r] = fmaf(xv.y, bw0[j].y, a0[r]);
            a0[r] = fmaf(xv.z, bw0[j].z, a0[r]); a0[r] = fmaf(xv.w, bw0[j].w, a0[r]);
            a1[r] = fmaf(xv.x, bw1[j].x, a1[r]); a1[r] = fmaf(xv.y, bw1[j].y, a1[r]);
            a1[r] = fmaf(xv.z, bw1[j].z, a1[r]); a1[r] = fmaf(xv.w, bw1[j].w, a1[r]);
        }
    }

#pragma unroll
    for (int r = 0; r < K1_ROWS; ++r) {
        float v0 = a0[r], v1 = a1[r];
        v0 += __shfl_xor(v0, 8);  v1 += __shfl_xor(v1, 8);
        v0 += __shfl_xor(v0, 16); v1 += __shfl_xor(v1, 16);
        v0 += __shfl_xor(v0, 32); v1 += __shfl_xor(v1, 32);
        a0[r] = v0; a1[r] = v1;
    }
    if (lane < 8) {
#pragma unroll
        for (int r = 0; r < K1_ROWS; ++r) {
            red[wid][lane][r][0] = a0[r];
            red[wid][lane][r][1] = a1[r];
        }
    }
    __syncthreads();
    if (tid < K1_ROWS * 16) {
        const int r = tid >> 4, n = tid & 15;
        float v = red[0][n >> 1][r][n & 1] + red[1][n >> 1][r][n & 1]
                + red[2][n >> 1][r][n & 1] + red[3][n >> 1][r][n & 1];
        bx[(size_t)(row0 + r) * D_STATE + n] = v;
    }
}

// ---------------------------------------------------------------------------
// K2 (fused FIR + matvec + LN): 256 thr, 8 rows/block, grid 1024.
// R12 core + async-STAGE split on kb/bwin staging (loads to regs, then LDS).
// ---------------------------------------------------------------------------
#define KO_ROWS 8
__global__ __launch_bounds__(256, 3) void k_tail(const float* __restrict__ x,
                                                 const float* __restrict__ bxg,
                                                 const float* __restrict__ KbarT,
                                                 const float* __restrict__ Cw,
                                                 const float* __restrict__ Dp,
                                                 const float* __restrict__ gamma,
                                                 const float* __restrict__ beta,
                                                 float* __restrict__ out) {
    const int tid = threadIdx.x;
    const int row0 = blockIdx.x * KO_ROWS;
    const int lane = tid & 63, wid = tid >> 6;
    __shared__ float4 bwin[71][4];                 // rows row0-63 .. row0+7
    __shared__ float4 kb4[WIN][4];                 // [delta][nq]
    __shared__ float4 hm4[KO_ROWS][4];
    __shared__ float red_s[KO_ROWS][4], red_q[KO_ROWS][4];

    // (1) x prefetch first (HBM, deepest latency) — 8 rows in flight
    float4 xq[KO_ROWS];
#pragma unroll
    for (int r = 0; r < KO_ROWS; ++r)
        xq[r] = reinterpret_cast<const float4*>(x + (size_t)(row0 + r) * D_MODEL)[tid];

    // (2) kb + bwin loads into regs (L2-resident)
    const float4 kbv = reinterpret_cast<const float4*>(KbarT)[tid];
    const float4* bx4 = reinterpret_cast<const float4*>(bxg);
    const int j0 = tid >> 2, q0 = tid & 3;
    long g0 = (long)row0 - 63 + j0; if (g0 < 0) g0 = 0;
    const float4 bv0 = bx4[g0 * 4 + q0];
    float4 bv1 = {0.f, 0.f, 0.f, 0.f};
    const int f1 = tid + 256;                      // covers indices 256..283
    if (tid < 71 * 4 - 256) {
        const int j1 = f1 >> 2, q1 = f1 & 3;
        long g1 = (long)row0 - 63 + j1; if (g1 < 0) g1 = 0;
        bv1 = bx4[g1 * 4 + q1];
    }

    // (3) LDS writes
    kb4[tid >> 2][tid & 3] = kbv;
    bwin[j0][q0] = bv0;
    if (tid < 71 * 4 - 256) bwin[f1 >> 2][f1 & 3] = bv1;
    __syncthreads();

    // ---- FIR: tid = r*32 + dc*4 + nq ----
    {
        const int r_f = tid >> 5, dc = (tid >> 2) & 7, nq = tid & 3;
        const int t0 = row0 & (SEQ - 1);
        float4 acc = {0.f, 0.f, 0.f, 0.f};
        if (t0 >= WIN) {                           // full window for all 8 rows
#pragma unroll
            for (int j = 0; j < 8; ++j) {
                const int delta = dc * 8 + j;
                const float4 b = bwin[63 + r_f - delta][nq];
                const float4 k = kb4[delta][nq];
                acc.x = fmaf(k.x, b.x, acc.x); acc.y = fmaf(k.y, b.y, acc.y);
                acc.z = fmaf(k.z, b.z, acc.z); acc.w = fmaf(k.w, b.w, acc.w);
            }
        } else {                                   // warm-up rows: mask taps
            const int t = t0 + r_f;
#pragma unroll
            for (int j = 0; j < 8; ++j) {
                const int delta = dc * 8 + j;
                if (delta <= t) {
                    const float4 b = bwin[63 + r_f - delta][nq];
                    const float4 k = kb4[delta][nq];
                    acc.x = fmaf(k.x, b.x, acc.x); acc.y = fmaf(k.y, b.y, acc.y);
                    acc.z = fmaf(k.z, b.z, acc.z); acc.w = fmaf(k.w, b.w, acc.w);
                }
            }
        }
#pragma unroll
        for (int off = 4; off <= 16; off <<= 1) {
            acc.x += __shfl_xor(acc.x, off);
            acc.y += __shfl_xor(acc.y, off);
            acc.z += __shfl_xor(acc.z, off);
            acc.w += __shfl_xor(acc.w, off);
        }
        if (dc == 0) hm4[r_f][nq] = acc;
    }
    __syncthreads();

    // ---- matvec + D*x + LN partials: all 8 rows, no intermediate barrier ----
    float4 cw[4][4];
#pragma unroll
    for (int j = 0; j < 4; ++j) {
        const float4* p = reinterpret_cast<const float4*>(Cw + (size_t)(tid * 4 + j) * D_STATE);
#pragma unroll
        for (int q = 0; q < 4; ++q) cw[j][q] = p[q];
    }
    const float4 Dq = reinterpret_cast<const float4*>(Dp)[tid];
    const float4 gq = reinterpret_cast<const float4*>(gamma)[tid];
    const float4 bq = reinterpret_cast<const float4*>(beta)[tid];

    float4 y[KO_ROWS];
#pragma unroll
    for (int r = 0; r < KO_ROWS; ++r) {
        const float4 h0 = hm4[r][0], h1 = hm4[r][1], h2 = hm4[r][2], h3 = hm4[r][3];
        float4 v;
#pragma unroll
        for (int j = 0; j < 4; ++j) {
            float a = 0.f;
            a = fmaf(h0.x, cw[j][0].x, a); a = fmaf(h0.y, cw[j][0].y, a);
            a = fmaf(h0.z, cw[j][0].z, a); a = fmaf(h0.w, cw[j][0].w, a);
            a = fmaf(h1.x, cw[j][1].x, a); a = fmaf(h1.y, cw[j][1].y, a);
            a = fmaf(h1.z, cw[j][1].z, a); a = fmaf(h1.w, cw[j][1].w, a);
            a = fmaf(h2.x, cw[j][2].x, a); a = fmaf(h2.y, cw[j][2].y, a);
            a = fmaf(h2.z, cw[j][2].z, a); a = fmaf(h2.w, cw[j][2].w, a);
            a = fmaf(h3.x, cw[j][3].x, a); a = fmaf(h3.y, cw[j][3].y, a);
            a = fmaf(h3.z, cw[j][3].z, a); a = fmaf(h3.w, cw[j][3].w, a);
            ((float*)&v)[j] = a;
        }
        v.x = fmaf(Dq.x, xq[r].x, v.x);
        v.y = fmaf(Dq.y, xq[r].y, v.y);
        v.z = fmaf(Dq.z, xq[r].z, v.z);
        v.w = fmaf(Dq.w, xq[r].w, v.w);
        y[r] = v;

        float s  = v.x + v.y + v.z + v.w;
        float sq = v.x*v.x + v.y*v.y + v.z*v.z + v.w*v.w;
        s += __shfl_xor(s, 1);  sq += __shfl_xor(sq, 1);
        s += __shfl_xor(s, 2);  sq += __shfl_xor(sq, 2);
        s += __shfl_xor(s, 4);  sq += __shfl_xor(sq, 4);
        s += __shfl_xor(s, 8);  sq += __shfl_xor(sq, 8);
        s += __shfl_xor(s, 16); sq += __shfl_xor(sq, 16);
        s += __shfl_xor(s, 32); sq += __shfl_xor(sq, 32);
        if (lane == 0) { red_s[r][wid] = s; red_q[r][wid] = sq; }
    }
    __syncthreads();

#pragma unroll
    for (int r = 0; r < KO_ROWS; ++r) {
        const size_t row = row0 + r;
        const float ssum = red_s[r][0] + red_s[r][1] + red_s[r][2] + red_s[r][3];
        const float ssq  = red_q[r][0] + red_q[r][1] + red_q[r][2] + red_q[r][3];
        const float mu   = ssum * (1.0f / 1024.0f);
        const float var  = ssq * (1.0f / 1024.0f) - mu * mu;
        const float inv  = rsqrtf(var + 1e-5f);
        const float4 v = y[r];
        float4 o;
        o.x = fmaf((v.x - mu) * inv, gq.x, bq.x);
        o.y = fmaf((v.y - mu) * inv, gq.y, bq.y);
        o.z = fmaf((v.z - mu) * inv, gq.z, bq.z);
        o.w = fmaf((v.w - mu) * inv, gq.w, bq.w);
        reinterpret_cast<float4*>(out + row * D_MODEL)[tid] = o;
    }
}

extern "C" void kernel_launch(void* const* d_in, const int* in_sizes, int n_in,
                              void* d_out, int out_size, void* d_ws, size_t ws_size,
                              hipStream_t stream) {
    (void)in_sizes; (void)n_in; (void)out_size; (void)ws_size;
    const float* x     = (const float*)d_in[0];
    const float* A_log = (const float*)d_in[1];
    const float* B_w   = (const float*)d_in[2];
    const float* C_w   = (const float*)d_in[3];
    const float* Dp    = (const float*)d_in[4];
    const float* gamma = (const float*)d_in[5];
    const float* beta  = (const float*)d_in[6];
    float* out = (float*)d_out;

    float* bx = (float*)d_ws;                       // ROWS*16 floats (512 KB)
    float* kb = bx + (size_t)ROWS * D_STATE;        // WIN*16 floats (4 KB)

    k_proj<<<ROWS / K1_ROWS + D_STATE, 256, 0, stream>>>(x, B_w, A_log, bx, kb);
    k_tail<<<ROWS / KO_ROWS,           256, 0, stream>>>(x, bx, kb, C_w, Dp, gamma, beta, out);
}